// Round 1
// baseline (103.464 us; speedup 1.0000x reference)
//
#include <hip/hip_runtime.h>

// Dust: zero out pixels inside any of 100 small circles per image.
// img: (N=16, C=3, H=512, W=512) fp32; centers/radii: (N, A=100) int32.
// Strategy: block = one (image, 8-row stripe). Cull circles by row range
// into LDS (avg ~4 survive of 100), then stream float4 pixel-quads,
// computing a 4-bit in-circle mask once per spatial quad and applying it
// to all 3 channels. Pure HBM-bound copy otherwise.

#define H_DIM 512
#define W_DIM 512
#define N_IMG 16
#define C_DIM 3
#define A_CIR 100
#define ROWS_PER_BLK 8

__global__ __launch_bounds__(256) void dust_kernel(
    const float* __restrict__ img,
    const int* __restrict__ cy_g,
    const int* __restrict__ cx_g,
    const int* __restrict__ r_g,
    float* __restrict__ out)
{
    __shared__ int s_cy[A_CIR];
    __shared__ int s_cx[A_CIR];
    __shared__ int s_r2[A_CIR];
    __shared__ int s_cnt;

    const int tiles_per_img = H_DIM / ROWS_PER_BLK;      // 64
    const int n    = blockIdx.x / tiles_per_img;
    const int tile = blockIdx.x % tiles_per_img;
    const int y0   = tile * ROWS_PER_BLK;

    if (threadIdx.x == 0) s_cnt = 0;
    __syncthreads();

    // Row-range cull: keep circles whose [cy-r, cy+r] overlaps [y0, y0+ROWS-1].
    if (threadIdx.x < A_CIR) {
        const int cy = cy_g[n * A_CIR + threadIdx.x];
        const int cx = cx_g[n * A_CIR + threadIdx.x];
        const int r  = r_g [n * A_CIR + threadIdx.x];
        if (cy + r >= y0 && cy - r <= y0 + ROWS_PER_BLK - 1) {
            const int idx = atomicAdd(&s_cnt, 1);
            s_cy[idx] = cy;
            s_cx[idx] = cx;
            s_r2[idx] = r * r;
        }
    }
    __syncthreads();
    const int cnt = s_cnt;

    const float4* __restrict__ img4 = (const float4*)img;
    float4* __restrict__ out4 = (float4*)out;

    const int groups = ROWS_PER_BLK * W_DIM / 4;          // 1024 quads per tile
    const size_t chan_stride4 = (size_t)H_DIM * W_DIM / 4;
    const size_t img_base4 = (size_t)n * C_DIM * chan_stride4;

    for (int g = threadIdx.x; g < groups; g += blockDim.x) {
        const int row_in_tile = g >> 7;                   // g / (512/4)
        const int col4        = g & 127;                  // g % 128
        const int h = y0 + row_in_tile;
        const int w = col4 * 4;

        // 4-bit mask: bit i set -> pixel (h, w+i) inside some circle.
        unsigned mask = 0;
        for (int i = 0; i < cnt; ++i) {
            const int dy  = h - s_cy[i];
            const int dy2 = dy * dy;
            const int r2  = s_r2[i];
            const int dx  = w - s_cx[i];
            mask |= (dy2 + dx * dx             <= r2 ? 1u : 0u)
                  | (dy2 + (dx + 1) * (dx + 1) <= r2 ? 2u : 0u)
                  | (dy2 + (dx + 2) * (dx + 2) <= r2 ? 4u : 0u)
                  | (dy2 + (dx + 3) * (dx + 3) <= r2 ? 8u : 0u);
        }

        const size_t idx4 = img_base4 + ((size_t)h * W_DIM + w) / 4;
        #pragma unroll
        for (int c = 0; c < C_DIM; ++c) {
            float4 v = img4[idx4 + (size_t)c * chan_stride4];
            if (mask & 1u) v.x = 0.0f;
            if (mask & 2u) v.y = 0.0f;
            if (mask & 4u) v.z = 0.0f;
            if (mask & 8u) v.w = 0.0f;
            out4[idx4 + (size_t)c * chan_stride4] = v;
        }
    }
}

extern "C" void kernel_launch(void* const* d_in, const int* in_sizes, int n_in,
                              void* d_out, int out_size, void* d_ws, size_t ws_size,
                              hipStream_t stream) {
    const float* img = (const float*)d_in[0];
    const int* cy    = (const int*)d_in[1];
    const int* cx    = (const int*)d_in[2];
    const int* rr    = (const int*)d_in[3];
    float* out       = (float*)d_out;

    const int blocks = N_IMG * (H_DIM / ROWS_PER_BLK);    // 1024
    dust_kernel<<<blocks, 256, 0, stream>>>(img, cy, cx, rr, out);
}